// Round 1
// baseline (670.924 us; speedup 1.0000x reference)
//
#include <hip/hip_runtime.h>
#include <math.h>

#define NB 8
#define NH 768
#define NW 768
#define NHW (NH*NW)
#define NCEN 100
#define NPIX (NB*NHW)
#define RAD 10
#define KS 21

// ws header layout (ints):
// [0,32)  : present bitmask, 4 words per batch
// [32,40) : has_inst per batch
// [40,48) : any_near per batch
// [48,56) : bmax bits (uint, nonneg floats) per batch
#define HDR_PRESENT 0
#define HDR_HAS 32
#define HDR_NEAR 40
#define HDR_BMAX 48
#define HDR_INTS 64

__global__ void k_init(int* __restrict__ hdr) {
    int t = threadIdx.x;
    if (t < HDR_INTS) hdr[t] = 0;
}

// Scan instances -> present bitmask (per-batch, 100 ids -> 4 words)
__global__ void k_scan(const int* __restrict__ inst, int* __restrict__ hdr) {
    __shared__ unsigned sm[4];
    int t = threadIdx.x;
    if (t < 4) sm[t] = 0;
    __syncthreads();
    int g = blockIdx.x * 256 + t;
    int iv = inst[g];
    if (iv > 0) atomicOr(&sm[iv >> 5], 1u << (iv & 31));
    __syncthreads();
    int b = (blockIdx.x * 256) / NHW;   // HW % 256 == 0, blocks never span batches
    if (t < 4 && sm[t]) atomicOr((unsigned*)&hdr[HDR_PRESENT + b * 4 + t], sm[t]);
}

// gt_centers output (B*100*2) + has_inst derivation
__global__ void k_small(const float* __restrict__ centers, int* __restrict__ hdr,
                        float* __restrict__ gt) {
    int t = threadIdx.x;
    if (t < NB * NCEN) {
        int b = t / NCEN, k = t - b * NCEN;
        float vx = 0.f, vy = 0.f;
        if (k >= 1) {
            unsigned w = (unsigned)hdr[HDR_PRESENT + b * 4 + (k >> 5)];
            if ((w >> (k & 31)) & 1u) {
                vx = centers[(b * NCEN + (k - 1)) * 2 + 1];  // swapped: x=centers[...,1]
                vy = centers[(b * NCEN + (k - 1)) * 2 + 0];
            }
        }
        gt[t * 2 + 0] = vx;
        gt[t * 2 + 1] = vy;
    } else if (t < NB * NCEN + NB) {
        int b = t - NB * NCEN;
        unsigned any = ((unsigned)hdr[HDR_PRESENT + b * 4] & 0xFFFFFFFEu)  // drop id 0
                     | (unsigned)hdr[HDR_PRESENT + b * 4 + 1]
                     | (unsigned)hdr[HDR_PRESENT + b * 4 + 2]
                     | (unsigned)hdr[HDR_PRESENT + b * 4 + 3];
        hdr[HDR_HAS + b] = any ? 1 : 0;
    }
}

// Per-pixel channels 0..4 + zero channels 6..12 + any_near flag
__global__ void k_main(const int* __restrict__ inst, const float* __restrict__ centers,
                       int* __restrict__ hdr, float* __restrict__ out) {
    int g = blockIdx.x * 256 + threadIdx.x;
    int b = g / NHW;
    int p = g - b * NHW;
    int i = p / NW;
    int j = p - i * NW;

    int iv = inst[g];
    bool valid = iv > 0;
    int idx = iv - 1;
    idx = idx < 0 ? 0 : (idx > NCEN - 1 ? NCEN - 1 : idx);
    float cy = centers[(b * NCEN + idx) * 2 + 0];
    float cx = centers[(b * NCEN + idx) * 2 + 1];
    float gcx = valid ? cx : -10000.f;
    float gcy = valid ? cy : -10000.f;
    float X = gcx - (float)i;
    float Y = gcy - (float)j;
    bool near = (fabsf(X) < 3.f) && (fabsf(Y) < 3.f);
    int hib = hdr[HDR_HAS + b];
    float ignore = (hib != 0) ? (near ? 0.f : 1.f) : 1.f;
    float m = valid ? 1.f : 0.f;
    float R = sqrtf(X * X + Y * Y) * m;
    float th = atan2f(Y, X);
    float theta = (hib != 0) ? th : 0.f;
    float s, c;
    sincosf(th, &s, &c);
    s = valid ? s : 0.f;     // after M-normalization this is exactly sin(th) masked
    c = valid ? c : 0.f;

    if (near) hdr[HDR_NEAR + b] = 1;  // same-value race, fine

    size_t base = (size_t)b * 13 * NHW + (size_t)p;
    out[base + 0 * (size_t)NHW] = R;
    out[base + 1 * (size_t)NHW] = theta;
    out[base + 2 * (size_t)NHW] = s;
    out[base + 3 * (size_t)NHW] = c;
    out[base + 4 * (size_t)NHW] = ignore;
#pragma unroll
    for (int ch = 6; ch < 13; ++ch) out[base + (size_t)ch * NHW] = 0.f;
}

__device__ __forceinline__ void blur_weights(float* w) {
    if (threadIdx.x == 0) {
        float v[KS];
        float s = 0.f;
        for (int k = 0; k < KS; k++) {
            float x = (float)(k - RAD) * 0.5f;       // x / SIGMA, SIGMA=2
            v[k] = expf(-0.5f * x * x);
            s += v[k];
        }
        for (int k = 0; k < KS; k++) w[k] = v[k] / s;
    }
}

// Horizontal 21-tap pass: input = 1 - ignore (read from mat ch4), output -> tmp
__global__ void k_blur_h(const float* __restrict__ out, float* __restrict__ tmp) {
    __shared__ float w[KS];
    blur_weights(w);
    __syncthreads();
    int g = blockIdx.x * 256 + threadIdx.x;
    int b = g / NHW;
    int p = g - b * NHW;
    int i = p / NW;
    int j = p - i * NW;
    const float* row = out + (size_t)b * 13 * NHW + 4 * (size_t)NHW + (size_t)i * NW;
    float acc = 0.f;
#pragma unroll
    for (int k = 0; k < KS; k++) {
        int jj = j + k - RAD;
        jj = jj < 0 ? -jj : (jj >= NW ? 2 * NW - 2 - jj : jj);  // reflect
        acc += w[k] * (1.f - row[jj]);
    }
    tmp[g] = acc;
}

// Vertical 21-tap pass: tmp -> mat ch5 (raw blur), plus per-batch max
__global__ void k_blur_v(const float* __restrict__ tmp, float* __restrict__ out,
                         unsigned* __restrict__ bmax) {
    __shared__ float w[KS];
    __shared__ unsigned smax;
    blur_weights(w);
    if (threadIdx.x == 0) smax = 0u;
    __syncthreads();
    int g = blockIdx.x * 256 + threadIdx.x;
    int b = g / NHW;
    int p = g - b * NHW;
    int i = p / NW;
    int j = p - i * NW;
    const float* tb = tmp + (size_t)b * NHW;
    float acc = 0.f;
#pragma unroll
    for (int k = 0; k < KS; k++) {
        int ii = i + k - RAD;
        ii = ii < 0 ? -ii : (ii >= NH ? 2 * NH - 2 - ii : ii);  // reflect
        acc += w[k] * tb[(size_t)ii * NW + j];
    }
    out[(size_t)b * 13 * NHW + 5 * (size_t)NHW + (size_t)p] = acc;
    atomicMax(&smax, __float_as_uint(acc));  // acc >= 0 -> monotone as uint
    __syncthreads();
    if (threadIdx.x == 0) atomicMax(&bmax[b], smax);
}

// Normalize ch5 in place: cmask = any_near ? blur / max(bmax,1e-12) : 0
__global__ void k_norm(const int* __restrict__ hdr, float* __restrict__ out) {
    int g = blockIdx.x * 256 + threadIdx.x;
    int b = g / NHW;
    int p = g - b * NHW;
    float* c5 = out + (size_t)b * 13 * NHW + 5 * (size_t)NHW;
    float bl = c5[p];
    float bm = __uint_as_float((unsigned)hdr[HDR_BMAX + b]);
    float cm = (hdr[HDR_NEAR + b] != 0) ? bl / fmaxf(bm, 1e-12f) : 0.f;
    c5[p] = cm;
}

extern "C" void kernel_launch(void* const* d_in, const int* in_sizes, int n_in,
                              void* d_out, int out_size, void* d_ws, size_t ws_size,
                              hipStream_t stream) {
    const int* inst = (const int*)d_in[0];
    const float* centers = (const float*)d_in[1];
    float* out = (float*)d_out;
    int* hdr = (int*)d_ws;
    float* tmp = (float*)((char*)d_ws + 256);
    float* gt = out + (size_t)NB * 13 * NHW;

    int nblk = NPIX / 256;  // 18432

    k_init<<<1, 64, 0, stream>>>(hdr);
    k_scan<<<nblk, 256, 0, stream>>>(inst, hdr);
    k_small<<<1, 1024, 0, stream>>>(centers, hdr, gt);
    k_main<<<nblk, 256, 0, stream>>>(inst, centers, hdr, out);
    k_blur_h<<<nblk, 256, 0, stream>>>(out, tmp);
    k_blur_v<<<nblk, 256, 0, stream>>>(tmp, out, (unsigned*)(hdr + HDR_BMAX));
    k_norm<<<nblk, 256, 0, stream>>>(hdr, out);
}

// Round 2
// 300.937 us; speedup vs baseline: 2.2294x; 2.2294x over previous
//
#include <hip/hip_runtime.h>
#include <math.h>

#define NB 8
#define NH 768
#define NW 768
#define NHW (NH*NW)
#define NCEN 100
#define NPIX (NB*NHW)
#define RAD 10
#define KS 21

#define TS 64
#define HALO 10
#define MS (TS + 2*HALO)          // 84
#define TILES_X (NW / TS)         // 12
#define TILES_Y (NH / TS)         // 12
#define TILES_PER_B (TILES_X * TILES_Y)  // 144

// ws header layout (ints):
#define HDR_PRESENT 0    // [0,32): present bitmask, 4 words per batch
#define HDR_HAS 32       // [32,40): has_inst per batch
#define HDR_NEAR 40      // [40,48): any_near per batch
#define HDR_BMAX 48      // [48,56): bmax bits (uint, nonneg floats) per batch
#define HDR_INTS 64

__device__ __forceinline__ int refl(int i, int n) {
    i = i < 0 ? -i : i;
    return i >= n ? 2 * n - 2 - i : i;
}

__global__ void k_init(int* __restrict__ hdr) {
    int t = threadIdx.x;
    if (t < HDR_INTS) hdr[t] = 0;
}

// instances -> present bitmask. int4 loads, wave OR-reduce, LDS stage, 4 global atomics/block.
// 1152 blocks x 256 threads x 16 ints = NPIX. Block covers 4096 ints; NHW%4096==0 -> no batch straddle.
__global__ void k_scan(const int4* __restrict__ inst4, int* __restrict__ hdr) {
    __shared__ unsigned sm[4];
    int t = threadIdx.x;
    if (t < 4) sm[t] = 0;
    __syncthreads();
    unsigned m0 = 0, m1 = 0, m2 = 0, m3 = 0;
    size_t base = (size_t)blockIdx.x * 1024 + t;   // int4 units
    int b = (int)((size_t)blockIdx.x * 4096 / NHW);
#pragma unroll
    for (int q = 0; q < 4; q++) {
        int4 v = inst4[base + (size_t)q * 256];
        int a[4] = {v.x, v.y, v.z, v.w};
#pragma unroll
        for (int e = 0; e < 4; e++) {
            int iv = a[e];
            if (iv > 0) {
                unsigned bit = 1u << (iv & 31);
                int w = iv >> 5;
                if (w == 0) m0 |= bit; else if (w == 1) m1 |= bit;
                else if (w == 2) m2 |= bit; else m3 |= bit;
            }
        }
    }
#pragma unroll
    for (int off = 32; off >= 1; off >>= 1) {
        m0 |= __shfl_xor(m0, off);
        m1 |= __shfl_xor(m1, off);
        m2 |= __shfl_xor(m2, off);
        m3 |= __shfl_xor(m3, off);
    }
    if ((t & 63) == 0) {
        if (m0) atomicOr(&sm[0], m0);
        if (m1) atomicOr(&sm[1], m1);
        if (m2) atomicOr(&sm[2], m2);
        if (m3) atomicOr(&sm[3], m3);
    }
    __syncthreads();
    if (t < 4 && sm[t]) atomicOr((unsigned*)&hdr[HDR_PRESENT + b * 4 + t], sm[t]);
}

// gt_centers output (B*100*2) + has_inst derivation
__global__ void k_small(const float* __restrict__ centers, int* __restrict__ hdr,
                        float* __restrict__ gt) {
    int t = threadIdx.x;
    if (t < NB * NCEN) {
        int b = t / NCEN, k = t - b * NCEN;
        float vx = 0.f, vy = 0.f;
        if (k >= 1) {
            unsigned w = (unsigned)hdr[HDR_PRESENT + b * 4 + (k >> 5)];
            if ((w >> (k & 31)) & 1u) {
                vx = centers[(b * NCEN + (k - 1)) * 2 + 1];
                vy = centers[(b * NCEN + (k - 1)) * 2 + 0];
            }
        }
        gt[t * 2 + 0] = vx;
        gt[t * 2 + 1] = vy;
    } else if (t < NB * NCEN + NB) {
        int b = t - NB * NCEN;
        unsigned any = ((unsigned)hdr[HDR_PRESENT + b * 4] & 0xFFFFFFFEu)
                     | (unsigned)hdr[HDR_PRESENT + b * 4 + 1]
                     | (unsigned)hdr[HDR_PRESENT + b * 4 + 2]
                     | (unsigned)hdr[HDR_PRESENT + b * 4 + 3];
        hdr[HDR_HAS + b] = any ? 1 : 0;
    }
}

// Fused: near-mask -> H blur -> V blur (all in LDS) + per-pixel ch0..4 + zeros + raw ch5
// + per-batch blur max + any_near flag.  One 64x64 tile per block.
__global__ __launch_bounds__(256) void k_fused(const int* __restrict__ inst,
                                               const float* __restrict__ centers,
                                               int* __restrict__ hdr,
                                               float* __restrict__ out) {
    __shared__ float s_cen[2 * NCEN];
    __shared__ float s_mask[MS * MS];   // 28224 B
    __shared__ float s_hbuf[MS * TS];   // 21504 B
    __shared__ float s_w[KS];
    __shared__ float s_red[4];

    int t = threadIdx.x;
    int tile = blockIdx.x;
    int b = tile / TILES_PER_B;
    int tr = tile - b * TILES_PER_B;
    int ti0 = (tr / TILES_X) * TS;
    int tj0 = (tr - (tr / TILES_X) * TILES_X) * TS;

    if (t == 0) {
        float v[KS];
        float sum = 0.f;
        for (int k = 0; k < KS; k++) {
            float x = (float)(k - RAD) * 0.5f;   // x/SIGMA, SIGMA=2
            v[k] = expf(-0.5f * x * x);
            sum += v[k];
        }
        for (int k = 0; k < KS; k++) s_w[k] = v[k] / sum;
    }
    for (int k = t; k < 2 * NCEN; k += 256) s_cen[k] = centers[b * 2 * NCEN + k];
    int has = hdr[HDR_HAS + b];
    __syncthreads();

    // ---- phase 1: near mask over halo region (reflected indices) ----
    int anynear = 0;
    const int* instb = inst + (size_t)b * NHW;
    for (int e = t; e < MS * MS; e += 256) {
        int r = e / MS, c = e - r * MS;
        int gi = refl(ti0 + r - HALO, NH);
        int gj = refl(tj0 + c - HALO, NW);
        int iv = instb[gi * NW + gj];
        float mv = 0.f;
        if (has && iv > 0) {
            int idx = iv - 1;
            float cy = s_cen[2 * idx];
            float cx = s_cen[2 * idx + 1];
            float X = cx - (float)gi;
            float Y = cy - (float)gj;
            if (fabsf(X) < 3.f && fabsf(Y) < 3.f) { mv = 1.f; anynear = 1; }
        }
        s_mask[e] = mv;
    }
    if (anynear) hdr[HDR_NEAR + b] = 1;
    __syncthreads();

    // ---- phase 2: horizontal 21-tap into s_hbuf ----
    for (int e = t; e < MS * TS; e += 256) {
        int r = e >> 6, c = e & 63;
        const float* mrow = &s_mask[r * MS + c];
        float acc = 0.f;
#pragma unroll
        for (int k = 0; k < KS; k++) acc += s_w[k] * mrow[k];
        s_hbuf[e] = acc;
    }
    __syncthreads();

    // ---- phase 3: vertical 21-tap + per-pixel channels ----
    float wmax = 0.f;
    float* outb = out + (size_t)b * 13 * NHW;
    for (int e = t; e < TS * TS; e += 256) {
        int r = e >> 6, c = e & 63;
        float blur = 0.f;
#pragma unroll
        for (int k = 0; k < KS; k++) blur += s_w[k] * s_hbuf[(r + k) * TS + c];
        wmax = fmaxf(wmax, blur);

        int gi = ti0 + r, gj = tj0 + c;
        int p = gi * NW + gj;
        int iv = instb[p];
        bool valid = iv > 0;
        int idx = iv - 1;
        idx = idx < 0 ? 0 : idx;
        float cy = s_cen[2 * idx];
        float cx = s_cen[2 * idx + 1];
        float gcx = valid ? cx : -10000.f;
        float gcy = valid ? cy : -10000.f;
        float X = gcx - (float)gi;
        float Y = gcy - (float)gj;
        bool near = (fabsf(X) < 3.f) && (fabsf(Y) < 3.f);
        float ignore = (has != 0) ? (near ? 0.f : 1.f) : 1.f;
        float m = valid ? 1.f : 0.f;
        float R2 = X * X + Y * Y;
        float R = sqrtf(R2) * m;
        float rinv = R2 > 0.f ? rsqrtf(R2) : 0.f;
        float s = valid ? Y * rinv : 0.f;                 // sin(atan2(Y,X)) masked
        float cth = valid ? (R2 > 0.f ? X * rinv : 1.f) : 0.f;
        float th = atan2f(Y, X);
        float theta = (has != 0) ? th : 0.f;

        size_t base = (size_t)p;
        outb[base + 0 * (size_t)NHW] = R;
        outb[base + 1 * (size_t)NHW] = theta;
        outb[base + 2 * (size_t)NHW] = s;
        outb[base + 3 * (size_t)NHW] = cth;
        outb[base + 4 * (size_t)NHW] = ignore;
        outb[base + 5 * (size_t)NHW] = blur;
#pragma unroll
        for (int ch = 6; ch < 13; ++ch) outb[base + (size_t)ch * NHW] = 0.f;
    }

    // ---- block-level max of blur -> global per-batch atomicMax ----
#pragma unroll
    for (int off = 32; off >= 1; off >>= 1) wmax = fmaxf(wmax, __shfl_down(wmax, off));
    if ((t & 63) == 0) s_red[t >> 6] = wmax;
    __syncthreads();
    if (t == 0) {
        float bm = fmaxf(fmaxf(s_red[0], s_red[1]), fmaxf(s_red[2], s_red[3]));
        atomicMax((unsigned*)&hdr[HDR_BMAX + b], __float_as_uint(bm));  // blur >= 0
    }
}

// Normalize ch5 in place (float4): cmask = any_near ? blur / max(bmax,1e-12) : 0
__global__ void k_norm(const int* __restrict__ hdr, float* __restrict__ out) {
    int g = blockIdx.x * 256 + threadIdx.x;       // over NPIX/4
    int b = g / (NHW / 4);
    int p4 = g - b * (NHW / 4);
    float4* c5 = (float4*)(out + (size_t)b * 13 * NHW + 5 * (size_t)NHW);
    float4 v = c5[p4];
    float bm = __uint_as_float((unsigned)hdr[HDR_BMAX + b]);
    float sc = (hdr[HDR_NEAR + b] != 0) ? 1.f / fmaxf(bm, 1e-12f) : 0.f;
    v.x *= sc; v.y *= sc; v.z *= sc; v.w *= sc;
    c5[p4] = v;
}

extern "C" void kernel_launch(void* const* d_in, const int* in_sizes, int n_in,
                              void* d_out, int out_size, void* d_ws, size_t ws_size,
                              hipStream_t stream) {
    const int* inst = (const int*)d_in[0];
    const float* centers = (const float*)d_in[1];
    float* out = (float*)d_out;
    int* hdr = (int*)d_ws;
    float* gt = out + (size_t)NB * 13 * NHW;

    k_init<<<1, 64, 0, stream>>>(hdr);
    k_scan<<<NPIX / 4096, 256, 0, stream>>>((const int4*)inst, hdr);
    k_small<<<1, 1024, 0, stream>>>(centers, hdr, gt);
    k_fused<<<NB * TILES_PER_B, 256, 0, stream>>>(inst, centers, hdr, out);
    k_norm<<<NPIX / 1024, 256, 0, stream>>>(hdr, out);
}

// Round 4
// 300.787 us; speedup vs baseline: 2.2306x; 1.0005x over previous
//
#include <hip/hip_runtime.h>
#include <math.h>

#define NB 8
#define NH 768
#define NW 768
#define NHW (NH*NW)
#define NCEN 100
#define NPIX (NB*NHW)
#define RAD 10
#define KS 21

#define TS 64
#define HALO 10
#define MS (TS + 2*HALO)          // 84
#define TILES_X (NW / TS)         // 12
#define TILES_PER_B (TILES_X * TILES_X)  // 144
#define SCAN_BLKS (NPIX / 4096)   // 1152
#define BLKS_PER_B (NHW / 4096)   // 144

// ws layout (ints):
#define HDR_HAS 32       // [32,40): has_inst per batch
#define HDR_NEAR 40      // [40,48): any_near per batch
#define HDR_BMAX 48      // [48,56): bmax bits (uint, nonneg floats) per batch
#define HDR_BLOCKMASK 64 // [64, 64+SCAN_BLKS*4): per-block present masks (4 words each)

typedef float f4 __attribute__((ext_vector_type(4)));  // native vector for nontemporal stores

__device__ __forceinline__ int refl(int i, int n) {
    i = i < 0 ? -i : i;
    return i >= n ? 2 * n - 2 - i : i;
}

// instances -> per-block present bitmask (plain stores, no init required).
// 1152 blocks x 256 threads x 16 ints = NPIX; NHW%4096==0 -> no batch straddle.
__global__ void k_scan(const int4* __restrict__ inst4, int* __restrict__ hdr) {
    __shared__ unsigned sm[4];
    int t = threadIdx.x;
    if (t < 4) sm[t] = 0;
    __syncthreads();
    unsigned m0 = 0, m1 = 0, m2 = 0, m3 = 0;
    size_t base = (size_t)blockIdx.x * 1024 + t;   // int4 units
#pragma unroll
    for (int q = 0; q < 4; q++) {
        int4 v = inst4[base + (size_t)q * 256];
        int a[4] = {v.x, v.y, v.z, v.w};
#pragma unroll
        for (int e = 0; e < 4; e++) {
            int iv = a[e];
            if (iv > 0) {
                unsigned bit = 1u << (iv & 31);
                int w = iv >> 5;
                if (w == 0) m0 |= bit; else if (w == 1) m1 |= bit;
                else if (w == 2) m2 |= bit; else m3 |= bit;
            }
        }
    }
#pragma unroll
    for (int off = 32; off >= 1; off >>= 1) {
        m0 |= __shfl_xor(m0, off);
        m1 |= __shfl_xor(m1, off);
        m2 |= __shfl_xor(m2, off);
        m3 |= __shfl_xor(m3, off);
    }
    if ((t & 63) == 0) {
        if (m0) atomicOr(&sm[0], m0);
        if (m1) atomicOr(&sm[1], m1);
        if (m2) atomicOr(&sm[2], m2);
        if (m3) atomicOr(&sm[3], m3);
    }
    __syncthreads();
    if (t < 4) ((unsigned*)&hdr[HDR_BLOCKMASK])[blockIdx.x * 4 + t] = sm[t];
}

// Reduce block masks -> present; gt_centers output; has_inst; zero NEAR/BMAX.
__global__ void k_small(const float* __restrict__ centers, int* __restrict__ hdr,
                        float* __restrict__ gt) {
    __shared__ unsigned s_pres[32];
    int t = threadIdx.x;
    const unsigned* bm = (const unsigned*)&hdr[HDR_BLOCKMASK];
    if (t < 32) {
        int b = t >> 2, wi = t & 3;
        unsigned acc = 0;
        for (int k = 0; k < BLKS_PER_B; k++) acc |= bm[(b * BLKS_PER_B + k) * 4 + wi];
        s_pres[t] = acc;
    }
    if (t >= 40 && t < 56) hdr[t] = 0;   // NEAR + BMAX
    __syncthreads();
    if (t < NB * NCEN) {
        int b = t / NCEN, k = t - b * NCEN;
        float vx = 0.f, vy = 0.f;
        if (k >= 1) {
            unsigned w = s_pres[b * 4 + (k >> 5)];
            if ((w >> (k & 31)) & 1u) {
                vx = centers[(b * NCEN + (k - 1)) * 2 + 1];
                vy = centers[(b * NCEN + (k - 1)) * 2 + 0];
            }
        }
        gt[t * 2 + 0] = vx;
        gt[t * 2 + 1] = vy;
    } else if (t < NB * NCEN + NB) {
        int b = t - NB * NCEN;
        unsigned any = (s_pres[b * 4] & 0xFFFFFFFEu)
                     | s_pres[b * 4 + 1] | s_pres[b * 4 + 2] | s_pres[b * 4 + 3];
        hdr[HDR_HAS + b] = any ? 1 : 0;
    }
}

// Fused: near-mask -> H blur -> V blur (LDS) + all per-pixel channels (float4 stores)
__global__ __launch_bounds__(256) void k_fused(const int* __restrict__ inst,
                                               const float* __restrict__ centers,
                                               int* __restrict__ hdr,
                                               float* __restrict__ out) {
    __shared__ float s_cen[2 * NCEN];
    __shared__ float s_mask[MS * MS];   // 28224 B
    __shared__ float s_hbuf[MS * TS];   // 21504 B
    __shared__ float s_w[KS];
    __shared__ float s_red[4];

    int t = threadIdx.x;
    int tile = blockIdx.x;
    int b = tile / TILES_PER_B;
    int tr = tile - b * TILES_PER_B;
    int ti0 = (tr / TILES_X) * TS;
    int tj0 = (tr - (tr / TILES_X) * TILES_X) * TS;

    if (t == 0) {
        float v[KS];
        float sum = 0.f;
        for (int k = 0; k < KS; k++) {
            float x = (float)(k - RAD) * 0.5f;   // x/SIGMA, SIGMA=2
            v[k] = expf(-0.5f * x * x);
            sum += v[k];
        }
        for (int k = 0; k < KS; k++) s_w[k] = v[k] / sum;
    }
    for (int k = t; k < 2 * NCEN; k += 256) s_cen[k] = centers[b * 2 * NCEN + k];
    int has = hdr[HDR_HAS + b];
    __syncthreads();

    // ---- phase 1: near mask over halo region (reflected indices) ----
    int anynear = 0;
    const int* instb = inst + (size_t)b * NHW;
    for (int e = t; e < MS * MS; e += 256) {
        int r = e / MS, c = e - r * MS;
        int gi = refl(ti0 + r - HALO, NH);
        int gj = refl(tj0 + c - HALO, NW);
        int iv = instb[gi * NW + gj];
        float mv = 0.f;
        if (has && iv > 0) {
            int idx = iv - 1;
            float cy = s_cen[2 * idx];
            float cx = s_cen[2 * idx + 1];
            float X = cx - (float)gi;
            float Y = cy - (float)gj;
            if (fabsf(X) < 3.f && fabsf(Y) < 3.f) { mv = 1.f; anynear = 1; }
        }
        s_mask[e] = mv;
    }
    if (anynear) hdr[HDR_NEAR + b] = 1;  // same-value race, fine
    __syncthreads();

    // ---- phase 2: horizontal 21-tap into s_hbuf ----
    for (int e = t; e < MS * TS; e += 256) {
        int r = e >> 6, c = e & 63;
        const float* mrow = &s_mask[r * MS + c];
        float acc = 0.f;
#pragma unroll
        for (int k = 0; k < KS; k++) acc += s_w[k] * mrow[k];
        s_hbuf[e] = acc;
    }
    __syncthreads();

    // ---- phase 3: vertical 21-tap + per-pixel channels, 4 px/thread, float4 I/O ----
    float wmax = 0.f;
    float* outb = out + (size_t)b * 13 * NHW;
    for (int q = t; q < TS * TS / 4; q += 256) {   // 1024 quads, 4 iters
        int r = q >> 4;
        int c0 = (q & 15) * 4;
        f4 blur = {0.f, 0.f, 0.f, 0.f};
#pragma unroll
        for (int k = 0; k < KS; k++) {
            f4 hv = *(const f4*)&s_hbuf[(r + k) * TS + c0];
            blur += s_w[k] * hv;
        }
        wmax = fmaxf(wmax, fmaxf(fmaxf(blur.x, blur.y), fmaxf(blur.z, blur.w)));

        int gi = ti0 + r, gj0 = tj0 + c0;
        int p0 = gi * NW + gj0;
        int4 ivv = *(const int4*)&instb[p0];
        int ia[4] = {ivv.x, ivv.y, ivv.z, ivv.w};
        f4 vR, vTh, vS, vC, vIg;
#pragma unroll
        for (int e = 0; e < 4; e++) {
            int iv = ia[e];
            bool valid = iv > 0;
            int idx = iv - 1;
            idx = idx < 0 ? 0 : idx;
            float cy = s_cen[2 * idx];
            float cx = s_cen[2 * idx + 1];
            float gcx = valid ? cx : -10000.f;
            float gcy = valid ? cy : -10000.f;
            float X = gcx - (float)gi;
            float Y = gcy - (float)(gj0 + e);
            bool near = (fabsf(X) < 3.f) && (fabsf(Y) < 3.f);
            vIg[e] = (has != 0) ? (near ? 0.f : 1.f) : 1.f;
            float m = valid ? 1.f : 0.f;
            float R2 = X * X + Y * Y;
            vR[e] = sqrtf(R2) * m;
            float rinv = R2 > 0.f ? rsqrtf(R2) : 0.f;
            vS[e] = valid ? Y * rinv : 0.f;                   // sin(atan2) masked
            vC[e] = valid ? (R2 > 0.f ? X * rinv : 1.f) : 0.f;
            float th = atan2f(Y, X);
            vTh[e] = (has != 0) ? th : 0.f;
        }
        __builtin_nontemporal_store(vR,   (f4*)&outb[(size_t)0 * NHW + p0]);
        __builtin_nontemporal_store(vTh,  (f4*)&outb[(size_t)1 * NHW + p0]);
        __builtin_nontemporal_store(vS,   (f4*)&outb[(size_t)2 * NHW + p0]);
        __builtin_nontemporal_store(vC,   (f4*)&outb[(size_t)3 * NHW + p0]);
        __builtin_nontemporal_store(vIg,  (f4*)&outb[(size_t)4 * NHW + p0]);
        __builtin_nontemporal_store(blur, (f4*)&outb[(size_t)5 * NHW + p0]);
        f4 z = {0.f, 0.f, 0.f, 0.f};
#pragma unroll
        for (int ch = 6; ch < 13; ++ch)
            __builtin_nontemporal_store(z, (f4*)&outb[(size_t)ch * NHW + p0]);
    }

    // ---- block-level max of blur -> global per-batch atomicMax ----
#pragma unroll
    for (int off = 32; off >= 1; off >>= 1) wmax = fmaxf(wmax, __shfl_down(wmax, off));
    if ((t & 63) == 0) s_red[t >> 6] = wmax;
    __syncthreads();
    if (t == 0) {
        float bmx = fmaxf(fmaxf(s_red[0], s_red[1]), fmaxf(s_red[2], s_red[3]));
        atomicMax((unsigned*)&hdr[HDR_BMAX + b], __float_as_uint(bmx));  // blur >= 0
    }
}

// Normalize ch5 in place (float4): cmask = any_near ? blur / max(bmax,1e-12) : 0
__global__ void k_norm(const int* __restrict__ hdr, float* __restrict__ out) {
    int g = blockIdx.x * 256 + threadIdx.x;       // over NPIX/4
    int b = g / (NHW / 4);
    int p4 = g - b * (NHW / 4);
    f4* c5 = (f4*)(out + (size_t)b * 13 * NHW + 5 * (size_t)NHW);
    f4 v = c5[p4];
    float bm = __uint_as_float((unsigned)hdr[HDR_BMAX + b]);
    float sc = (hdr[HDR_NEAR + b] != 0) ? 1.f / fmaxf(bm, 1e-12f) : 0.f;
    v *= sc;
    c5[p4] = v;
}

extern "C" void kernel_launch(void* const* d_in, const int* in_sizes, int n_in,
                              void* d_out, int out_size, void* d_ws, size_t ws_size,
                              hipStream_t stream) {
    const int* inst = (const int*)d_in[0];
    const float* centers = (const float*)d_in[1];
    float* out = (float*)d_out;
    int* hdr = (int*)d_ws;
    float* gt = out + (size_t)NB * 13 * NHW;

    k_scan<<<SCAN_BLKS, 256, 0, stream>>>((const int4*)inst, hdr);
    k_small<<<1, 1024, 0, stream>>>(centers, hdr, gt);
    k_fused<<<NB * TILES_PER_B, 256, 0, stream>>>(inst, centers, hdr, out);
    k_norm<<<NPIX / 1024, 256, 0, stream>>>(hdr, out);
}